// Round 16
// baseline (501.436 us; speedup 1.0000x reference)
//
#include <hip/hip_runtime.h>

#define N0 100000
#define N1 50000
#define N2 25000
#define E0 500000
#define E1 250000
#define N_TOT (3 * N1 + 3 * N2)
#define NE_ALL (3 * E0 + 3 * E1)
#define BNODE 512
#define NBUCK ((N_TOT + BNODE - 1) / BNODE)   // 440
#define BCAP 12288

typedef __attribute__((ext_vector_type(8))) short short8;
typedef __attribute__((ext_vector_type(4))) float f32x4;
typedef unsigned short ushort_t;
typedef unsigned int uint_t;

static __device__ __forceinline__ float lrelu(float x, float s) {
    return x >= 0.f ? x : s * x;
}

static __device__ __forceinline__ ushort_t f2bf(float f) {
    union { float f; uint_t u; } v; v.f = f;
    uint_t r = v.u + 0x7FFFu + ((v.u >> 16) & 1u);
    return (ushort_t)(r >> 16);
}

static __device__ __forceinline__ float bf_lo(uint_t u) {
    union { uint_t i; float f; } v; v.i = u << 16;
    return v.f;
}
static __device__ __forceinline__ float bf_hi(uint_t u) {
    union { uint_t i; float f; } v; v.i = u & 0xFFFF0000u;
    return v.f;
}

static __device__ __forceinline__ uint_t cvt2(float lo, float hi) {
    uint_t r;
    asm("v_cvt_pk_bf16_f32 %0, %1, %2" : "=v"(r) : "v"(lo), "v"(hi));
    return r;
}

// ================= MFMA GEMM (unchanged, proven) =================
template <int CT, int PLANES, int OUTMODE, int AB16, int OB16 = 0, int REPY = 0>
__global__ __launch_bounds__(256) void gemm_bf16(
    const void* __restrict__ A0, const void* __restrict__ A1,
    const void* __restrict__ A2, const void* __restrict__ A3,
    int nodes, const ushort_t* __restrict__ Bt, int cols,
    const float* __restrict__ biasA, const float* __restrict__ biasB,
    int colsplit, float slopeA, float slopeB,
    void* __restrict__ O1, int ld1, float* __restrict__ O2, int ld2,
    const float* __restrict__ glp, const float* __restrict__ aWp, int kreal,
    int repB = 0, int repO1 = 0, int repO2 = 0)
{
    constexpr int BCOLS = CT * 16;
    constexpr int NPANEL = (OUTMODE == 4) ? 2 : 1;
    constexpr int SCOLS = BCOLS * NPANEL;
    constexpr int CSTR = BCOLS + 4;
    constexpr int SH_B = SCOLS * 256;
    constexpr int SH_C = 64 * CSTR * 4 + ((OUTMODE == 4) ? 2048 : 0);
    constexpr int SHSZ = SH_B > SH_C ? SH_B : SH_C;
    constexpr int AELT = AB16 ? 2 : 4;
    __shared__ char sh[SHSZ];
    float* Cs = (float*)sh;

    const int Mrows = nodes * PLANES;
    const int row0 = blockIdx.x * 128;
    const int repy = REPY ? blockIdx.y : 0;
    const int cbase = REPY ? 0 : blockIdx.y * BCOLS;
    const ushort_t* Btp = Bt + (REPY ? (size_t)repy * repB : 0);
    ushort_t* O1p = (ushort_t*)O1 + (REPY ? (size_t)repy * repO1 : 0);
    float* O2p = O2 + (REPY ? (size_t)repy * repO2 : 0);
    const int tid = threadIdx.x;

    for (int u = tid; u < SCOLS * 16; u += 256) {
        int cl = u >> 4;
        int q = u & 15;
        int off = cl * 256 + q * 16;
        off ^= (cl & 7) << 4;
        int c;
        if (OUTMODE == 4)
            c = (cl < BCOLS) ? (cbase + cl) : (128 + cbase + (cl - BCOLS));
        else
            c = cbase + cl;
        uint4 d = make_uint4(0, 0, 0, 0);
        if (c < cols) d = *(const uint4*)(Btp + (size_t)c * 128 + q * 8);
        *(uint4*)(sh + off) = d;
    }
    __syncthreads();

    const int wv = tid >> 6;
    const int l = tid & 63;
    const int kg = l >> 4;
    const char* aptr[2];
    #pragma unroll
    for (int rt = 0; rt < 2; ++rt) {
        int rg = row0 + wv * 32 + rt * 16 + (l & 15);
        if (rg >= Mrows) rg = Mrows - 1;
        int node, pl;
        if (PLANES == 1) { node = rg; pl = 0; }
        else { node = rg / PLANES; pl = rg % PLANES; }
        const void* base = (pl == 0) ? A0 : (pl == 1) ? A1 : (pl == 2) ? A2 : A3;
        aptr[rt] = (const char*)base + ((size_t)node * 128 + kg * 8) * AELT;
    }

    f32x4 acc[2][CT];
    f32x4 accV[2][(OUTMODE == 4) ? CT : 1];
    #pragma unroll
    for (int a = 0; a < 2; ++a) {
        #pragma unroll
        for (int b = 0; b < CT; ++b)
            #pragma unroll
            for (int q = 0; q < 4; ++q) acc[a][b][q] = 0.f;
        if (OUTMODE == 4)
            #pragma unroll
            for (int b = 0; b < CT; ++b)
                #pragma unroll
                for (int q = 0; q < 4; ++q) accV[a][b][q] = 0.f;
    }

    #pragma unroll
    for (int kt = 0; kt < 4; ++kt) {
        short8 af[2];
        #pragma unroll
        for (int rt = 0; rt < 2; ++rt) {
            if (AB16) {
                af[rt] = *(const short8*)(aptr[rt] + (size_t)kt * 64);
            } else {
                const float4* p = (const float4*)(aptr[rt] + (size_t)kt * 128);
                float4 x0 = p[0];
                float4 x1 = p[1];
                union { uint_t u[4]; short8 s; } u;
                u.u[0] = cvt2(x0.x, x0.y);
                u.u[1] = cvt2(x0.z, x0.w);
                u.u[2] = cvt2(x1.x, x1.y);
                u.u[3] = cvt2(x1.z, x1.w);
                af[rt] = u.s;
            }
        }
        #pragma unroll
        for (int ct = 0; ct < CT; ++ct) {
            int off = ((ct * 16 + (l & 15)) * 256) + kt * 64 + (l >> 4) * 16;
            off ^= (l & 7) << 4;
            short8 bfr = *(const short8*)(sh + off);
            acc[0][ct] = __builtin_amdgcn_mfma_f32_16x16x32_bf16(af[0], bfr, acc[0][ct], 0, 0, 0);
            acc[1][ct] = __builtin_amdgcn_mfma_f32_16x16x32_bf16(af[1], bfr, acc[1][ct], 0, 0, 0);
            if (OUTMODE == 4) {
                int offv = ((BCOLS + ct * 16 + (l & 15)) * 256) + kt * 64 + (l >> 4) * 16;
                offv ^= (l & 7) << 4;
                short8 bfv = *(const short8*)(sh + offv);
                accV[0][ct] = __builtin_amdgcn_mfma_f32_16x16x32_bf16(af[0], bfv, accV[0][ct], 0, 0, 0);
                accV[1][ct] = __builtin_amdgcn_mfma_f32_16x16x32_bf16(af[1], bfv, accV[1][ct], 0, 0, 0);
            }
        }
    }

    if (OUTMODE == 4) {
        const int node0 = row0 >> 2;
        float* e_sh = (float*)(sh + 64 * CSTR * 4);
        float* w_sh = e_sh + 256;
        float4 aw0 = ((const float4*)aWp)[0];
        float4 aw1 = ((const float4*)aWp)[1];
        float4 aw2 = ((const float4*)aWp)[2];
        float4 aw3 = ((const float4*)aWp)[3];
        #pragma unroll
        for (int rt = 0; rt < 2; ++rt) {
            __syncthreads();
            #pragma unroll
            for (int ct = 0; ct < CT; ++ct) {
                int col = ct * 16 + (l & 15);
                float br_ = biasA[cbase + col];
                int lrow = wv * 16 + (l >> 4) * 4;
                #pragma unroll
                for (int j = 0; j < 4; ++j)
                    Cs[(lrow + j) * CSTR + col] = acc[rt][ct][j] + br_;
            }
            __syncthreads();
            {
                int row = tid >> 2, head = tid & 3;
                int rg = row0 + ((row >> 4) << 5) + rt * 16 + (row & 15);
                int node = rg >> 2;
                if (node > nodes - 1) node = nodes - 1;
                const float* zr = &Cs[row * CSTR + head * 16];
                const float* glr = glp + (size_t)node * 128 + cbase + head * 16;
                float4 c0 = *(const float4*)(zr);
                float4 c1 = *(const float4*)(zr + 4);
                float4 c2 = *(const float4*)(zr + 8);
                float4 c3 = *(const float4*)(zr + 12);
                float4 g0 = *(const float4*)(glr);
                float4 g1 = *(const float4*)(glr + 4);
                float4 g2 = *(const float4*)(glr + 8);
                float4 g3 = *(const float4*)(glr + 12);
                float e =
                    lrelu(c0.x + g0.x, 0.01f) * aw0.x + lrelu(c0.y + g0.y, 0.01f) * aw0.y +
                    lrelu(c0.z + g0.z, 0.01f) * aw0.z + lrelu(c0.w + g0.w, 0.01f) * aw0.w +
                    lrelu(c1.x + g1.x, 0.01f) * aw1.x + lrelu(c1.y + g1.y, 0.01f) * aw1.y +
                    lrelu(c1.z + g1.z, 0.01f) * aw1.z + lrelu(c1.w + g1.w, 0.01f) * aw1.w +
                    lrelu(c2.x + g2.x, 0.01f) * aw2.x + lrelu(c2.y + g2.y, 0.01f) * aw2.y +
                    lrelu(c2.z + g2.z, 0.01f) * aw2.z + lrelu(c2.w + g2.w, 0.01f) * aw2.w +
                    lrelu(c3.x + g3.x, 0.01f) * aw3.x + lrelu(c3.y + g3.y, 0.01f) * aw3.y +
                    lrelu(c3.z + g3.z, 0.01f) * aw3.z + lrelu(c3.w + g3.w, 0.01f) * aw3.w;
                e_sh[row * 4 + head] = e;
            }
            __syncthreads();
            if (tid < 64) {
                int q = tid >> 2, head = tid & 3;
                int rho0 = (q >> 2) * 16 + (q & 3) * 4;
                float e0 = e_sh[(rho0 + 0) * 4 + head];
                float e1 = e_sh[(rho0 + 1) * 4 + head];
                float e2 = e_sh[(rho0 + 2) * 4 + head];
                float e3 = (kreal == 4) ? e_sh[(rho0 + 3) * 4 + head] : -1e30f;
                float m = fmaxf(fmaxf(e0, e1), fmaxf(e2, e3));
                float x0 = __expf(e0 - m), x1 = __expf(e1 - m), x2 = __expf(e2 - m);
                float x3 = (kreal == 4) ? __expf(e3 - m) : 0.f;
                float inv = 1.f / (x0 + x1 + x2 + x3);
                w_sh[q * 16 + 0 + head] = x0 * inv;
                w_sh[q * 16 + 4 + head] = x1 * inv;
                w_sh[q * 16 + 8 + head] = x2 * inv;
                w_sh[q * 16 + 12 + head] = x3 * inv;
            }
            __syncthreads();
            #pragma unroll
            for (int ct = 0; ct < CT; ++ct) {
                int col = ct * 16 + (l & 15);
                float bp_ = biasB[cbase + col];
                int lrow = wv * 16 + (l >> 4) * 4;
                #pragma unroll
                for (int j = 0; j < 4; ++j)
                    Cs[(lrow + j) * CSTR + col] = accV[rt][ct][j] + bp_;
            }
            __syncthreads();
            {
                int nidx = tid >> 4;
                int c4 = tid & 15;
                int nl = rt * 4 + (nidx >> 2) * 8 + (nidx & 3);
                int gn = node0 + nl;
                if (gn < nodes) {
                    int head = c4 >> 2;
                    float4 o = make_float4(0.f, 0.f, 0.f, 0.f);
                    #pragma unroll
                    for (int k = 0; k < 4; ++k) {
                        int rho = (nidx >> 2) * 16 + (nidx & 3) * 4 + k;
                        float wk = w_sh[nidx * 16 + k * 4 + head];
                        float4 v4 = *(const float4*)&Cs[rho * CSTR + c4 * 4];
                        o.x += wk * v4.x; o.y += wk * v4.y;
                        o.z += wk * v4.z; o.w += wk * v4.w;
                    }
                    o.x = lrelu(o.x, 0.01f); o.y = lrelu(o.y, 0.01f);
                    o.z = lrelu(o.z, 0.01f); o.w = lrelu(o.w, 0.01f);
                    if (OB16) {
                        uint2 pk;
                        pk.x = cvt2(o.x, o.y);
                        pk.y = cvt2(o.z, o.w);
                        *(uint2*)((ushort_t*)O1 + (size_t)gn * 128 + cbase + c4 * 4) = pk;
                    } else {
                        *(float4*)((float*)O1 + (size_t)gn * 128 + cbase + c4 * 4) = o;
                    }
                }
            }
        }
        return;
    }

    #pragma unroll
    for (int rt = 0; rt < 2; ++rt) {
        __syncthreads();
        #pragma unroll
        for (int ct = 0; ct < CT; ++ct) {
            int c = cbase + ct * 16 + (l & 15);
            float bias_ = 0.f, slope_ = 1.f;
            if (c < colsplit) {
                if (biasA) bias_ = biasA[c];
                slope_ = slopeA;
            } else if (c < cols) {
                if (biasB) bias_ = biasB[c - colsplit];
                slope_ = slopeB;
            }
            int lrow = wv * 16 + (l >> 4) * 4;
            #pragma unroll
            for (int j = 0; j < 4; ++j) {
                float v = acc[rt][ct][j] + bias_;
                v = v >= 0.f ? v : v * slope_;
                Cs[(lrow + j) * CSTR + ct * 16 + (l & 15)] = v;
            }
        }
        __syncthreads();
        for (int i = tid; i < 64 * CT * 4; i += 256) {
            int rho = i / (CT * 4);
            int c4 = i - rho * (CT * 4);
            int col = c4 * 4;
            int gcol = cbase + col;
            int rg = row0 + rt * 16 + (rho >> 4) * 32 + (rho & 15);
            if (rg >= Mrows || gcol >= cols) continue;
            float4 v = *(const float4*)&Cs[rho * CSTR + col];
            if (gcol < 128) {
                uint2 pk;
                pk.x = cvt2(v.x, v.y);
                pk.y = cvt2(v.z, v.w);
                *(uint2*)(O1p + (size_t)rg * ld1 + gcol) = pk;
            } else {
                *(float4*)(O2p + (size_t)rg * ld2 + (gcol - 128)) = v;
            }
        }
    }
}

// ================= merged prologue =================
struct P2Job { const float* Wa; const float* Wb; ushort_t* dst; };
struct PrepArgs {
    const float* conv_W; const float* conv_al; const float* conv_ar;
    ushort_t* pconvA;
    P2Job j[6];
    const float* x; ushort_t* x16;
};

__global__ __launch_bounds__(128) void prep_all(PrepArgs pa)
{
    const int bid = blockIdx.x;
    const int k = threadIdx.x;
    if (bid < 816) {
        int jj = bid / 136, c = bid - jj * 136;
        const float* W = pa.conv_W + (size_t)jj * 16384;
        float v;
        if (c < 128) {
            v = W[k * 128 + c];
        } else {
            int idx = c - 128;
            int g = idx & 3;
            const float* a = ((idx < 4) ? pa.conv_al : pa.conv_ar) + jj * 128;
            float s = 0.f;
            for (int d = 0; d < 32; ++d) s += W[k * 128 + g * 32 + d] * a[g * 32 + d];
            v = s;
        }
        pa.pconvA[(size_t)jj * 136 * 128 + c * 128 + k] = f2bf(v);
    } else if (bid < 816 + 1536) {
        int b2 = bid - 816;
        int jj = b2 >> 8, c = b2 & 255;
        const float* W = (c < 128) ? pa.j[jj].Wa : pa.j[jj].Wb;
        int cc = c & 127;
        pa.j[jj].dst[c * 128 + k] = f2bf(W[k * 128 + cc]);
    } else {
        int idx = (bid - 2352) * 128 + k;
        if (idx < N0 * 16) {
            const float4* p = (const float4*)(pa.x + (size_t)idx * 8);
            float4 a = p[0], b = p[1];
            uint4 pk;
            pk.x = cvt2(a.x, a.y); pk.y = cvt2(a.z, a.w);
            pk.z = cvt2(b.x, b.y); pk.w = cvt2(b.z, b.w);
            *(uint4*)(pa.x16 + (size_t)idx * 8) = pk;
        }
    }
}

// ================= binned CSR build =================
static __device__ __forceinline__ void edge_decode(
    int idx, const int* __restrict__ src0, const int* __restrict__ dst0,
    const int* __restrict__ src1, const int* __restrict__ dst1,
    int& src, int& gnode)
{
    if (idx < 3 * E0) {
        src = src0[idx];
        gnode = (idx / E0) * N1 + dst0[idx];
    } else {
        int k = idx - 3 * E0;
        src = src1[k];
        gnode = 3 * N1 + (k / E1) * N2 + dst1[k];
    }
}

// 16384 edges/block (64 iters, dual decode): long contiguous runs per
// (block,bucket) -> full-line writebacks; 4x fewer global bcur atomics.
__global__ __launch_bounds__(256) void bin_pass64(
    const int* __restrict__ src0, const int* __restrict__ dst0,
    const int* __restrict__ src1, const int* __restrict__ dst1,
    int* __restrict__ bcur, uint_t* __restrict__ tmp)
{
    __shared__ int lcnt[512];
    __shared__ int lbase[512];
    const int tid = threadIdx.x;
    const int e0 = blockIdx.x * 16384;
    for (int t = tid; t < 512; t += 256) lcnt[t] = 0;
    __syncthreads();
    for (int i = 0; i < 64; ++i) {
        int idx = e0 + i * 256 + tid;
        if (idx < NE_ALL) {
            int s, g;
            edge_decode(idx, src0, dst0, src1, dst1, s, g);
            atomicAdd(&lcnt[g >> 9], 1);
        }
    }
    __syncthreads();
    for (int t = tid; t < 512; t += 256) {
        int c = lcnt[t];
        lbase[t] = c ? atomicAdd(&bcur[t], c) : 0;
        lcnt[t] = 0;
    }
    __syncthreads();
    for (int i = 0; i < 64; ++i) {
        int idx = e0 + i * 256 + tid;
        if (idx < NE_ALL) {
            int s, g;
            edge_decode(idx, src0, dst0, src1, dst1, s, g);
            int b = g >> 9;
            int p = lbase[b] + atomicAdd(&lcnt[b], 1);
            if (p < BCAP)
                tmp[(size_t)b * BCAP + p] = (uint_t)((s << 9) | (g & 511));
        }
    }
}

// build_pass with fused bucket-base scan
__global__ __launch_bounds__(256) void build_pass2(
    const int* __restrict__ bcur, const uint_t* __restrict__ tmp,
    int* __restrict__ offs, int* __restrict__ csr)
{
    __shared__ int cnt[512];
    __shared__ int offl[512];
    __shared__ int ps[256];
    __shared__ int pbase[512];
    const int tid = threadIdx.x;
    const int b = blockIdx.x;

    int v0 = (2 * tid < NBUCK) ? bcur[2 * tid] : 0;
    int v1 = (2 * tid + 1 < NBUCK) ? bcur[2 * tid + 1] : 0;
    ps[tid] = v0 + v1;
    __syncthreads();
    for (int off = 1; off < 256; off <<= 1) {
        int x = (tid >= off) ? ps[tid - off] : 0;
        __syncthreads();
        ps[tid] += x;
        __syncthreads();
    }
    {
        int ex = ps[tid] - (v0 + v1);
        pbase[2 * tid] = ex;
        pbase[2 * tid + 1] = ex + v0;
    }
    __syncthreads();
    const int base = pbase[b];

    int nE = bcur[b];
    if (nE > BCAP) nE = BCAP;
    const int node0 = b * BNODE;
    const uint_t* tp = tmp + (size_t)b * BCAP;

    for (int t = tid; t < 512; t += 256) cnt[t] = 0;
    __syncthreads();
    for (int i = tid; i < nE; i += 256)
        atomicAdd(&cnt[tp[i] & 511], 1);
    __syncthreads();
    int a0 = cnt[2 * tid], a1 = cnt[2 * tid + 1];
    ps[tid] = a0 + a1;
    __syncthreads();
    for (int off = 1; off < 256; off <<= 1) {
        int x = (tid >= off) ? ps[tid - off] : 0;
        __syncthreads();
        ps[tid] += x;
        __syncthreads();
    }
    int ex = ps[tid] - (a0 + a1);
    offl[2 * tid] = ex;
    offl[2 * tid + 1] = ex + a0;
    __syncthreads();
    for (int t = tid; t < BNODE; t += 256) {
        int gn = node0 + t;
        if (gn < N_TOT) offs[gn] = base + offl[t];
    }
    if (b == NBUCK - 1 && tid == 0) offs[N_TOT] = base + nE;
    for (int t = tid; t < 512; t += 256) cnt[t] = 0;
    __syncthreads();
    for (int i = tid; i < nE; i += 256) {
        uint_t pk = tp[i];
        int ld = pk & 511;
        int p = atomicAdd(&cnt[ld], 1);
        csr[base + offl[ld] + p] = (int)(pk >> 9);
    }
}

// ====== softmax gather: 8 slots x 8 lanes (16 P-loads in flight/wave) ======
__global__ __launch_bounds__(256) void gat_gather8(
    const int* __restrict__ csrc, const int* __restrict__ offs,
    int base0, int nPerRep,
    const float* __restrict__ elr, int elrStride,
    const ushort_t* __restrict__ P, int pStride,
    ushort_t* __restrict__ out, int outStride)
{
    const int wv = threadIdx.x >> 6;
    const int g = blockIdx.x * 4 + wv;
    if (g >= 3 * nPerRep) return;
    const int rep = g / nPerRep;
    const int node = g - rep * nPerRep;
    const float* elrp = elr + (size_t)rep * elrStride;
    const ushort_t* Pp = P + (size_t)rep * pStride;
    ushort_t* outp = out + (size_t)rep * outStride;

    const int l = threadIdx.x & 63;
    const uint_t lane8 = l & 7;          // cols lane8*16 .. +16
    const int slot = l >> 3;             // 8 edge slots
    const uint_t hg = lane8 >> 1;        // head for this 16-col group
    const int beg = offs[base0 + g], end = offs[base0 + g + 1];
    const float erg = elrp[(uint_t)node * 8u + 4u + hg];
    float den = 0.f;
    float a[16];
    #pragma unroll
    for (int q = 0; q < 16; ++q) a[q] = 0.f;
    for (int i = beg + slot; i < end; i += 8) {
        uint_t s = (uint_t)csrc[i];
        float w = __expf(lrelu(elrp[s * 8u + hg] + erg, 0.2f));
        const ushort_t* rp = Pp + s * 128u + lane8 * 16u;
        uint4 da = *(const uint4*)(rp);
        uint4 db = *(const uint4*)(rp + 8);
        den += w;
        a[0] += w * bf_lo(da.x); a[1] += w * bf_hi(da.x);
        a[2] += w * bf_lo(da.y); a[3] += w * bf_hi(da.y);
        a[4] += w * bf_lo(da.z); a[5] += w * bf_hi(da.z);
        a[6] += w * bf_lo(da.w); a[7] += w * bf_hi(da.w);
        a[8] += w * bf_lo(db.x); a[9] += w * bf_hi(db.x);
        a[10] += w * bf_lo(db.y); a[11] += w * bf_hi(db.y);
        a[12] += w * bf_lo(db.z); a[13] += w * bf_hi(db.z);
        a[14] += w * bf_lo(db.w); a[15] += w * bf_hi(db.w);
    }
    #pragma unroll
    for (int m = 8; m <= 32; m <<= 1) {
        den += __shfl_xor(den, m);
        #pragma unroll
        for (int q = 0; q < 16; ++q) a[q] += __shfl_xor(a[q], m);
    }
    if (slot == 0) {
        float inv = (end > beg) ? 1.f / den : 0.f;
        uint4 pk0, pk1;
        pk0.x = cvt2(lrelu(a[0] * inv, 0.01f), lrelu(a[1] * inv, 0.01f));
        pk0.y = cvt2(lrelu(a[2] * inv, 0.01f), lrelu(a[3] * inv, 0.01f));
        pk0.z = cvt2(lrelu(a[4] * inv, 0.01f), lrelu(a[5] * inv, 0.01f));
        pk0.w = cvt2(lrelu(a[6] * inv, 0.01f), lrelu(a[7] * inv, 0.01f));
        pk1.x = cvt2(lrelu(a[8] * inv, 0.01f), lrelu(a[9] * inv, 0.01f));
        pk1.y = cvt2(lrelu(a[10] * inv, 0.01f), lrelu(a[11] * inv, 0.01f));
        pk1.z = cvt2(lrelu(a[12] * inv, 0.01f), lrelu(a[13] * inv, 0.01f));
        pk1.w = cvt2(lrelu(a[14] * inv, 0.01f), lrelu(a[15] * inv, 0.01f));
        ushort_t* op = outp + (uint_t)node * 128u + lane8 * 16u;
        *(uint4*)(op) = pk0;
        *(uint4*)(op + 8) = pk1;
    }
}

// ================= final linear 128 -> 2 =================
__global__ __launch_bounds__(256) void lin_kernel(
    const float* __restrict__ H, const float* __restrict__ W,
    const float* __restrict__ b, float* __restrict__ out, int n)
{
    int idx = blockIdx.x * 256 + threadIdx.x;
    int node = idx >> 1, c = idx & 1;
    if (node >= n) return;
    float acc = 0.f;
    for (int k = 0; k < 128; ++k)
        acc += H[(size_t)node * 128 + k] * W[k * 2 + c];
    out[(size_t)node * 2 + c] = acc + b[c];
}

extern "C" void kernel_launch(void* const* d_in, const int* in_sizes, int n_in,
                              void* d_out, int out_size, void* d_ws, size_t ws_size,
                              hipStream_t stream)
{
    (void)in_sizes; (void)n_in; (void)out_size; (void)ws_size;
    const float* x       = (const float*)d_in[0];
    const int*   src0    = (const int*)d_in[1];
    const int*   dst0    = (const int*)d_in[2];
    const int*   src1    = (const int*)d_in[3];
    const int*   dst1    = (const int*)d_in[4];
    const float* conv_W  = (const float*)d_in[5];
    const float* conv_al = (const float*)d_in[6];
    const float* conv_ar = (const float*)d_in[7];
    const float* feat_W  = (const float*)d_in[8];
    const float* feat_b  = (const float*)d_in[9];
    const float* relWl_W = (const float*)d_in[10];
    const float* relWl_b = (const float*)d_in[11];
    const float* relWr_W = (const float*)d_in[12];
    const float* relWr_b = (const float*)d_in[13];
    const float* relP_W  = (const float*)d_in[14];
    const float* relP_b  = (const float*)d_in[15];
    const float* rela_W  = (const float*)d_in[16];
    const float* proj_W  = (const float*)d_in[18];
    const float* proj_b  = (const float*)d_in[19];
    const float* hopWl_W = (const float*)d_in[20];
    const float* hopWl_b = (const float*)d_in[21];
    const float* hopWr_W = (const float*)d_in[22];
    const float* hopWr_b = (const float*)d_in[23];
    const float* hopP_W  = (const float*)d_in[24];
    const float* hopP_b  = (const float*)d_in[25];
    const float* hopa_W  = (const float*)d_in[26];
    const float* lin_W   = (const float*)d_in[28];
    const float* lin_b   = (const float*)d_in[29];
    float* out = (float*)d_out;

    // ---- workspace layout (~233 MB) ----
    char* base = (char*)d_ws;
    size_t off = 0;
    auto alloc = [&](size_t bytes) -> void* {
        void* p = base + off;
        off += (bytes + 255) & ~(size_t)255;
        return p;
    };
    ushort_t* P     = (ushort_t*)alloc((size_t)3 * N0 * 128 * 2);
    float* elr      = (float*)alloc((size_t)3 * N0 * 8 * 4);
    ushort_t* x16   = (ushort_t*)alloc((size_t)N0 * 128 * 2);
    ushort_t* F     = (ushort_t*)alloc((size_t)3 * N1 * 128 * 2);
    ushort_t* F3    = (ushort_t*)alloc((size_t)N1 * 128 * 2);
    ushort_t* h1    = (ushort_t*)alloc((size_t)N1 * 128 * 2);
    ushort_t* h2    = (ushort_t*)alloc((size_t)N2 * 128 * 2);
    float* glbuf    = (float*)alloc((size_t)N1 * 128 * 4);
    float* glhop    = (float*)alloc((size_t)N2 * 128 * 4);
    int*   csr_all  = (int*)alloc((size_t)NE_ALL * 4);
    int*   offs     = (int*)alloc((size_t)(N_TOT + 1) * 4);
    int*   bcur     = (int*)alloc(512 * 4);
    ushort_t* pconvA = (ushort_t*)alloc((size_t)6 * 136 * 128 * 2);
    ushort_t* p2L0 = (ushort_t*)alloc(256 * 128 * 2);
    ushort_t* p2L1 = (ushort_t*)alloc(256 * 128 * 2);
    ushort_t* pE   = (ushort_t*)alloc(256 * 128 * 2);
    ushort_t* pF0  = (ushort_t*)alloc(256 * 128 * 2);
    ushort_t* pF1  = (ushort_t*)alloc(256 * 128 * 2);
    ushort_t* pG   = (ushort_t*)alloc(256 * 128 * 2);

    ushort_t* F0 = F;
    ushort_t* F1 = F + (size_t)N1 * 128;
    ushort_t* F2 = F + (size_t)2 * N1 * 128;
    ushort_t* hopp0 = F0;
    float* hout  = glbuf;
    uint_t* tmp  = (uint_t*)F;

    // ---- merged prologue ----
    PrepArgs pa;
    pa.conv_W = conv_W; pa.conv_al = conv_al; pa.conv_ar = conv_ar; pa.pconvA = pconvA;
    pa.j[0] = {feat_W, relWl_W, p2L0};
    pa.j[1] = {feat_W + 16384, relWl_W + 16384, p2L1};
    pa.j[2] = {proj_W, hopWl_W, pE};
    pa.j[3] = {relWr_W, relP_W, pF0};
    pa.j[4] = {relWr_W + 16384, relP_W + 16384, pF1};
    pa.j[5] = {hopWr_W, hopP_W, pG};
    pa.x = x; pa.x16 = x16;
    prep_all<<<816 + 1536 + 12500, 128, 0, stream>>>(pa);

    // ---- binned CSR build ----
    hipMemsetAsync(bcur, 0, 512 * 4, stream);
    bin_pass64<<<(NE_ALL + 16383) / 16384, 256, 0, stream>>>(src0, dst0, src1, dst1, bcur, tmp);
    build_pass2<<<NBUCK, 256, 0, stream>>>(bcur, tmp, offs, csr_all);

    // ---- layer 0 ----
    gemm_bf16<9, 1, 1, 1, 0, 1><<<dim3((N0 + 127) / 128, 3), 256, 0, stream>>>(
        x16, x16, x16, x16, N0, pconvA, 136, nullptr, nullptr, 128, 1.f, 1.f,
        P, 128, elr, 8, nullptr, nullptr, 0,
        136 * 128, N0 * 128, N0 * 8);
    gat_gather8<<<(3 * N1 + 3) / 4, 256, 0, stream>>>(
        csr_all, offs, 0, N1, elr, N0 * 8, P, N0 * 128, F, N1 * 128);
    gemm_bf16<8, 1, 1, 1><<<dim3((N1 + 127) / 128, 2), 256, 0, stream>>>(
        x16, x16, x16, x16, N1, p2L0, 256, feat_b, relWl_b, 128, 0.01f, 1.f,
        F3, 128, glbuf, 128, nullptr, nullptr, 0);
    gemm_bf16<4, 4, 4, 1, 1><<<dim3((N1 * 4 + 127) / 128, 2), 256, 0, stream>>>(
        F0, F1, F2, F3, N1, pF0, 256, relWr_b, relP_b, 128, 1.f, 1.f,
        h1, 128, nullptr, 0, glbuf, rela_W, 4);

    // ---- layer 1 ----
    gemm_bf16<9, 1, 1, 1, 0, 1><<<dim3((N1 + 127) / 128, 3), 256, 0, stream>>>(
        h1, h1, h1, h1, N1, pconvA + (size_t)3 * 136 * 128, 136,
        nullptr, nullptr, 128, 1.f, 1.f,
        P, 128, elr, 8, nullptr, nullptr, 0,
        136 * 128, N0 * 128, N0 * 8);
    gat_gather8<<<(3 * N2 + 3) / 4, 256, 0, stream>>>(
        csr_all, offs, 3 * N1, N2, elr, N0 * 8, P, N0 * 128, F, N1 * 128);
    gemm_bf16<8, 1, 1, 1><<<dim3((N2 + 127) / 128, 2), 256, 0, stream>>>(
        h1, h1, h1, h1, N2, p2L1, 256, feat_b + 128, relWl_b + 128, 128, 0.01f, 1.f,
        F3, 128, glbuf, 128, nullptr, nullptr, 0);
    gemm_bf16<4, 4, 4, 1, 1><<<dim3((N2 * 4 + 127) / 128, 2), 256, 0, stream>>>(
        F0, F1, F2, F3, N2, pF1, 256, relWr_b + 128, relP_b + 128, 128, 1.f, 1.f,
        h2, 128, nullptr, 0, glbuf, rela_W + 16, 4);

    // ---- proj + hop gl ----
    gemm_bf16<8, 1, 1, 1><<<dim3((N2 + 127) / 128, 2), 256, 0, stream>>>(
        x16, x16, x16, x16, N2, pE, 256, proj_b, hopWl_b, 128, 1.f, 1.f,
        hopp0, 128, glhop, 128, nullptr, nullptr, 0);

    // ---- hop attention over [proj, h1[:N2], h2] ----
    gemm_bf16<4, 4, 4, 1, 0><<<dim3((N2 * 4 + 127) / 128, 2), 256, 0, stream>>>(
        hopp0, h1, h2, hopp0, N2, pG, 256, hopWr_b, hopP_b, 128, 1.f, 1.f,
        hout, 128, nullptr, 0, glhop, hopa_W, 3);

    // ---- final linear ----
    lin_kernel<<<(N2 * 2 + 255) / 256, 256, 0, stream>>>(hout, lin_W, lin_b, out, N2);
}

// Round 17
// 424.208 us; speedup vs baseline: 1.1821x; 1.1821x over previous
//
#include <hip/hip_runtime.h>

#define N0 100000
#define N1 50000
#define N2 25000
#define E0 500000
#define E1 250000
#define N_TOT (3 * N1 + 3 * N2)
#define NE_ALL (3 * E0 + 3 * E1)
#define BNODE 512
#define NBUCK ((N_TOT + BNODE - 1) / BNODE)   // 440
#define BCAP 12288

typedef __attribute__((ext_vector_type(8))) short short8;
typedef __attribute__((ext_vector_type(4))) float f32x4;
typedef unsigned short ushort_t;
typedef unsigned int uint_t;

static __device__ __forceinline__ float lrelu(float x, float s) {
    return x >= 0.f ? x : s * x;
}

static __device__ __forceinline__ ushort_t f2bf(float f) {
    union { float f; uint_t u; } v; v.f = f;
    uint_t r = v.u + 0x7FFFu + ((v.u >> 16) & 1u);
    return (ushort_t)(r >> 16);
}

static __device__ __forceinline__ float bf_lo(uint_t u) {
    union { uint_t i; float f; } v; v.i = u << 16;
    return v.f;
}
static __device__ __forceinline__ float bf_hi(uint_t u) {
    union { uint_t i; float f; } v; v.i = u & 0xFFFF0000u;
    return v.f;
}

static __device__ __forceinline__ uint_t cvt2(float lo, float hi) {
    uint_t r;
    asm("v_cvt_pk_bf16_f32 %0, %1, %2" : "=v"(r) : "v"(lo), "v"(hi));
    return r;
}

// ================= MFMA GEMM (unchanged, proven) =================
template <int CT, int PLANES, int OUTMODE, int AB16, int OB16 = 0, int REPY = 0>
__global__ __launch_bounds__(256) void gemm_bf16(
    const void* __restrict__ A0, const void* __restrict__ A1,
    const void* __restrict__ A2, const void* __restrict__ A3,
    int nodes, const ushort_t* __restrict__ Bt, int cols,
    const float* __restrict__ biasA, const float* __restrict__ biasB,
    int colsplit, float slopeA, float slopeB,
    void* __restrict__ O1, int ld1, float* __restrict__ O2, int ld2,
    const float* __restrict__ glp, const float* __restrict__ aWp, int kreal,
    int repB = 0, int repO1 = 0, int repO2 = 0)
{
    constexpr int BCOLS = CT * 16;
    constexpr int NPANEL = (OUTMODE == 4) ? 2 : 1;
    constexpr int SCOLS = BCOLS * NPANEL;
    constexpr int CSTR = BCOLS + 4;
    constexpr int SH_B = SCOLS * 256;
    constexpr int SH_C = 64 * CSTR * 4 + ((OUTMODE == 4) ? 2048 : 0);
    constexpr int SHSZ = SH_B > SH_C ? SH_B : SH_C;
    constexpr int AELT = AB16 ? 2 : 4;
    __shared__ char sh[SHSZ];
    float* Cs = (float*)sh;

    const int Mrows = nodes * PLANES;
    const int row0 = blockIdx.x * 128;
    const int repy = REPY ? blockIdx.y : 0;
    const int cbase = REPY ? 0 : blockIdx.y * BCOLS;
    const ushort_t* Btp = Bt + (REPY ? (size_t)repy * repB : 0);
    ushort_t* O1p = (ushort_t*)O1 + (REPY ? (size_t)repy * repO1 : 0);
    float* O2p = O2 + (REPY ? (size_t)repy * repO2 : 0);
    const int tid = threadIdx.x;

    for (int u = tid; u < SCOLS * 16; u += 256) {
        int cl = u >> 4;
        int q = u & 15;
        int off = cl * 256 + q * 16;
        off ^= (cl & 7) << 4;
        int c;
        if (OUTMODE == 4)
            c = (cl < BCOLS) ? (cbase + cl) : (128 + cbase + (cl - BCOLS));
        else
            c = cbase + cl;
        uint4 d = make_uint4(0, 0, 0, 0);
        if (c < cols) d = *(const uint4*)(Btp + (size_t)c * 128 + q * 8);
        *(uint4*)(sh + off) = d;
    }
    __syncthreads();

    const int wv = tid >> 6;
    const int l = tid & 63;
    const int kg = l >> 4;
    const char* aptr[2];
    #pragma unroll
    for (int rt = 0; rt < 2; ++rt) {
        int rg = row0 + wv * 32 + rt * 16 + (l & 15);
        if (rg >= Mrows) rg = Mrows - 1;
        int node, pl;
        if (PLANES == 1) { node = rg; pl = 0; }
        else { node = rg / PLANES; pl = rg % PLANES; }
        const void* base = (pl == 0) ? A0 : (pl == 1) ? A1 : (pl == 2) ? A2 : A3;
        aptr[rt] = (const char*)base + ((size_t)node * 128 + kg * 8) * AELT;
    }

    f32x4 acc[2][CT];
    f32x4 accV[2][(OUTMODE == 4) ? CT : 1];
    #pragma unroll
    for (int a = 0; a < 2; ++a) {
        #pragma unroll
        for (int b = 0; b < CT; ++b)
            #pragma unroll
            for (int q = 0; q < 4; ++q) acc[a][b][q] = 0.f;
        if (OUTMODE == 4)
            #pragma unroll
            for (int b = 0; b < CT; ++b)
                #pragma unroll
                for (int q = 0; q < 4; ++q) accV[a][b][q] = 0.f;
    }

    #pragma unroll
    for (int kt = 0; kt < 4; ++kt) {
        short8 af[2];
        #pragma unroll
        for (int rt = 0; rt < 2; ++rt) {
            if (AB16) {
                af[rt] = *(const short8*)(aptr[rt] + (size_t)kt * 64);
            } else {
                const float4* p = (const float4*)(aptr[rt] + (size_t)kt * 128);
                float4 x0 = p[0];
                float4 x1 = p[1];
                union { uint_t u[4]; short8 s; } u;
                u.u[0] = cvt2(x0.x, x0.y);
                u.u[1] = cvt2(x0.z, x0.w);
                u.u[2] = cvt2(x1.x, x1.y);
                u.u[3] = cvt2(x1.z, x1.w);
                af[rt] = u.s;
            }
        }
        #pragma unroll
        for (int ct = 0; ct < CT; ++ct) {
            int off = ((ct * 16 + (l & 15)) * 256) + kt * 64 + (l >> 4) * 16;
            off ^= (l & 7) << 4;
            short8 bfr = *(const short8*)(sh + off);
            acc[0][ct] = __builtin_amdgcn_mfma_f32_16x16x32_bf16(af[0], bfr, acc[0][ct], 0, 0, 0);
            acc[1][ct] = __builtin_amdgcn_mfma_f32_16x16x32_bf16(af[1], bfr, acc[1][ct], 0, 0, 0);
            if (OUTMODE == 4) {
                int offv = ((BCOLS + ct * 16 + (l & 15)) * 256) + kt * 64 + (l >> 4) * 16;
                offv ^= (l & 7) << 4;
                short8 bfv = *(const short8*)(sh + offv);
                accV[0][ct] = __builtin_amdgcn_mfma_f32_16x16x32_bf16(af[0], bfv, accV[0][ct], 0, 0, 0);
                accV[1][ct] = __builtin_amdgcn_mfma_f32_16x16x32_bf16(af[1], bfv, accV[1][ct], 0, 0, 0);
            }
        }
    }

    if (OUTMODE == 4) {
        const int node0 = row0 >> 2;
        float* e_sh = (float*)(sh + 64 * CSTR * 4);
        float* w_sh = e_sh + 256;
        float4 aw0 = ((const float4*)aWp)[0];
        float4 aw1 = ((const float4*)aWp)[1];
        float4 aw2 = ((const float4*)aWp)[2];
        float4 aw3 = ((const float4*)aWp)[3];
        #pragma unroll
        for (int rt = 0; rt < 2; ++rt) {
            __syncthreads();
            #pragma unroll
            for (int ct = 0; ct < CT; ++ct) {
                int col = ct * 16 + (l & 15);
                float br_ = biasA[cbase + col];
                int lrow = wv * 16 + (l >> 4) * 4;
                #pragma unroll
                for (int j = 0; j < 4; ++j)
                    Cs[(lrow + j) * CSTR + col] = acc[rt][ct][j] + br_;
            }
            __syncthreads();
            {
                int row = tid >> 2, head = tid & 3;
                int rg = row0 + ((row >> 4) << 5) + rt * 16 + (row & 15);
                int node = rg >> 2;
                if (node > nodes - 1) node = nodes - 1;
                const float* zr = &Cs[row * CSTR + head * 16];
                const float* glr = glp + (size_t)node * 128 + cbase + head * 16;
                float4 c0 = *(const float4*)(zr);
                float4 c1 = *(const float4*)(zr + 4);
                float4 c2 = *(const float4*)(zr + 8);
                float4 c3 = *(const float4*)(zr + 12);
                float4 g0 = *(const float4*)(glr);
                float4 g1 = *(const float4*)(glr + 4);
                float4 g2 = *(const float4*)(glr + 8);
                float4 g3 = *(const float4*)(glr + 12);
                float e =
                    lrelu(c0.x + g0.x, 0.01f) * aw0.x + lrelu(c0.y + g0.y, 0.01f) * aw0.y +
                    lrelu(c0.z + g0.z, 0.01f) * aw0.z + lrelu(c0.w + g0.w, 0.01f) * aw0.w +
                    lrelu(c1.x + g1.x, 0.01f) * aw1.x + lrelu(c1.y + g1.y, 0.01f) * aw1.y +
                    lrelu(c1.z + g1.z, 0.01f) * aw1.z + lrelu(c1.w + g1.w, 0.01f) * aw1.w +
                    lrelu(c2.x + g2.x, 0.01f) * aw2.x + lrelu(c2.y + g2.y, 0.01f) * aw2.y +
                    lrelu(c2.z + g2.z, 0.01f) * aw2.z + lrelu(c2.w + g2.w, 0.01f) * aw2.w +
                    lrelu(c3.x + g3.x, 0.01f) * aw3.x + lrelu(c3.y + g3.y, 0.01f) * aw3.y +
                    lrelu(c3.z + g3.z, 0.01f) * aw3.z + lrelu(c3.w + g3.w, 0.01f) * aw3.w;
                e_sh[row * 4 + head] = e;
            }
            __syncthreads();
            if (tid < 64) {
                int q = tid >> 2, head = tid & 3;
                int rho0 = (q >> 2) * 16 + (q & 3) * 4;
                float e0 = e_sh[(rho0 + 0) * 4 + head];
                float e1 = e_sh[(rho0 + 1) * 4 + head];
                float e2 = e_sh[(rho0 + 2) * 4 + head];
                float e3 = (kreal == 4) ? e_sh[(rho0 + 3) * 4 + head] : -1e30f;
                float m = fmaxf(fmaxf(e0, e1), fmaxf(e2, e3));
                float x0 = __expf(e0 - m), x1 = __expf(e1 - m), x2 = __expf(e2 - m);
                float x3 = (kreal == 4) ? __expf(e3 - m) : 0.f;
                float inv = 1.f / (x0 + x1 + x2 + x3);
                w_sh[q * 16 + 0 + head] = x0 * inv;
                w_sh[q * 16 + 4 + head] = x1 * inv;
                w_sh[q * 16 + 8 + head] = x2 * inv;
                w_sh[q * 16 + 12 + head] = x3 * inv;
            }
            __syncthreads();
            #pragma unroll
            for (int ct = 0; ct < CT; ++ct) {
                int col = ct * 16 + (l & 15);
                float bp_ = biasB[cbase + col];
                int lrow = wv * 16 + (l >> 4) * 4;
                #pragma unroll
                for (int j = 0; j < 4; ++j)
                    Cs[(lrow + j) * CSTR + col] = accV[rt][ct][j] + bp_;
            }
            __syncthreads();
            {
                int nidx = tid >> 4;
                int c4 = tid & 15;
                int nl = rt * 4 + (nidx >> 2) * 8 + (nidx & 3);
                int gn = node0 + nl;
                if (gn < nodes) {
                    int head = c4 >> 2;
                    float4 o = make_float4(0.f, 0.f, 0.f, 0.f);
                    #pragma unroll
                    for (int k = 0; k < 4; ++k) {
                        int rho = (nidx >> 2) * 16 + (nidx & 3) * 4 + k;
                        float wk = w_sh[nidx * 16 + k * 4 + head];
                        float4 v4 = *(const float4*)&Cs[rho * CSTR + c4 * 4];
                        o.x += wk * v4.x; o.y += wk * v4.y;
                        o.z += wk * v4.z; o.w += wk * v4.w;
                    }
                    o.x = lrelu(o.x, 0.01f); o.y = lrelu(o.y, 0.01f);
                    o.z = lrelu(o.z, 0.01f); o.w = lrelu(o.w, 0.01f);
                    if (OB16) {
                        uint2 pk;
                        pk.x = cvt2(o.x, o.y);
                        pk.y = cvt2(o.z, o.w);
                        *(uint2*)((ushort_t*)O1 + (size_t)gn * 128 + cbase + c4 * 4) = pk;
                    } else {
                        *(float4*)((float*)O1 + (size_t)gn * 128 + cbase + c4 * 4) = o;
                    }
                }
            }
        }
        return;
    }

    #pragma unroll
    for (int rt = 0; rt < 2; ++rt) {
        __syncthreads();
        #pragma unroll
        for (int ct = 0; ct < CT; ++ct) {
            int c = cbase + ct * 16 + (l & 15);
            float bias_ = 0.f, slope_ = 1.f;
            if (c < colsplit) {
                if (biasA) bias_ = biasA[c];
                slope_ = slopeA;
            } else if (c < cols) {
                if (biasB) bias_ = biasB[c - colsplit];
                slope_ = slopeB;
            }
            int lrow = wv * 16 + (l >> 4) * 4;
            #pragma unroll
            for (int j = 0; j < 4; ++j) {
                float v = acc[rt][ct][j] + bias_;
                v = v >= 0.f ? v : v * slope_;
                Cs[(lrow + j) * CSTR + ct * 16 + (l & 15)] = v;
            }
        }
        __syncthreads();
        for (int i = tid; i < 64 * CT * 4; i += 256) {
            int rho = i / (CT * 4);
            int c4 = i - rho * (CT * 4);
            int col = c4 * 4;
            int gcol = cbase + col;
            int rg = row0 + rt * 16 + (rho >> 4) * 32 + (rho & 15);
            if (rg >= Mrows || gcol >= cols) continue;
            float4 v = *(const float4*)&Cs[rho * CSTR + col];
            if (gcol < 128) {
                uint2 pk;
                pk.x = cvt2(v.x, v.y);
                pk.y = cvt2(v.z, v.w);
                *(uint2*)(O1p + (size_t)rg * ld1 + gcol) = pk;
            } else {
                *(float4*)(O2p + (size_t)rg * ld2 + (gcol - 128)) = v;
            }
        }
    }
}

// ================= merged prologue =================
struct P2Job { const float* Wa; const float* Wb; ushort_t* dst; };
struct PrepArgs {
    const float* conv_W; const float* conv_al; const float* conv_ar;
    ushort_t* pconvA;
    P2Job j[6];
    const float* x; ushort_t* x16;
};

__global__ __launch_bounds__(128) void prep_all(PrepArgs pa)
{
    const int bid = blockIdx.x;
    const int k = threadIdx.x;
    if (bid < 816) {
        int jj = bid / 136, c = bid - jj * 136;
        const float* W = pa.conv_W + (size_t)jj * 16384;
        float v;
        if (c < 128) {
            v = W[k * 128 + c];
        } else {
            int idx = c - 128;
            int g = idx & 3;
            const float* a = ((idx < 4) ? pa.conv_al : pa.conv_ar) + jj * 128;
            float s = 0.f;
            for (int d = 0; d < 32; ++d) s += W[k * 128 + g * 32 + d] * a[g * 32 + d];
            v = s;
        }
        pa.pconvA[(size_t)jj * 136 * 128 + c * 128 + k] = f2bf(v);
    } else if (bid < 816 + 1536) {
        int b2 = bid - 816;
        int jj = b2 >> 8, c = b2 & 255;
        const float* W = (c < 128) ? pa.j[jj].Wa : pa.j[jj].Wb;
        int cc = c & 127;
        pa.j[jj].dst[c * 128 + k] = f2bf(W[k * 128 + cc]);
    } else {
        int idx = (bid - 2352) * 128 + k;
        if (idx < N0 * 16) {
            const float4* p = (const float4*)(pa.x + (size_t)idx * 8);
            float4 a = p[0], b = p[1];
            uint4 pk;
            pk.x = cvt2(a.x, a.y); pk.y = cvt2(a.z, a.w);
            pk.z = cvt2(b.x, b.y); pk.w = cvt2(b.z, b.w);
            *(uint4*)(pa.x16 + (size_t)idx * 8) = pk;
        }
    }
}

// ================= binned CSR build =================
static __device__ __forceinline__ void edge_decode(
    int idx, const int* __restrict__ src0, const int* __restrict__ dst0,
    const int* __restrict__ src1, const int* __restrict__ dst1,
    int& src, int& gnode)
{
    if (idx < 3 * E0) {
        src = src0[idx];
        gnode = (idx / E0) * N1 + dst0[idx];
    } else {
        int k = idx - 3 * E0;
        src = src1[k];
        gnode = 3 * N1 + (k / E1) * N2 + dst1[k];
    }
}

// single-decode, 4096 edges/block (550 blocks = full machine)
__global__ __launch_bounds__(256) void bin_pass(
    const int* __restrict__ src0, const int* __restrict__ dst0,
    const int* __restrict__ src1, const int* __restrict__ dst1,
    int* __restrict__ bcur, uint_t* __restrict__ tmp)
{
    __shared__ int lcnt[512];
    __shared__ int lbase[512];
    const int tid = threadIdx.x;
    const int e0 = blockIdx.x * 4096;
    int sv[16], gv[16];
    for (int t = tid; t < 512; t += 256) lcnt[t] = 0;
    __syncthreads();
    #pragma unroll
    for (int i = 0; i < 16; ++i) {
        int idx = e0 + i * 256 + tid;
        if (idx < NE_ALL) {
            edge_decode(idx, src0, dst0, src1, dst1, sv[i], gv[i]);
            atomicAdd(&lcnt[gv[i] >> 9], 1);
        } else {
            gv[i] = -1; sv[i] = 0;
        }
    }
    __syncthreads();
    for (int t = tid; t < 512; t += 256) {
        int c = lcnt[t];
        lbase[t] = c ? atomicAdd(&bcur[t], c) : 0;
        lcnt[t] = 0;
    }
    __syncthreads();
    #pragma unroll
    for (int i = 0; i < 16; ++i) {
        if (gv[i] >= 0) {
            int b = gv[i] >> 9;
            int p = lbase[b] + atomicAdd(&lcnt[b], 1);
            if (p < BCAP)
                tmp[(size_t)b * BCAP + p] = (uint_t)((sv[i] << 9) | (gv[i] & 511));
        }
    }
}

// build_pass with fused bucket-base scan
__global__ __launch_bounds__(256) void build_pass2(
    const int* __restrict__ bcur, const uint_t* __restrict__ tmp,
    int* __restrict__ offs, int* __restrict__ csr)
{
    __shared__ int cnt[512];
    __shared__ int offl[512];
    __shared__ int ps[256];
    __shared__ int pbase[512];
    const int tid = threadIdx.x;
    const int b = blockIdx.x;

    int v0 = (2 * tid < NBUCK) ? bcur[2 * tid] : 0;
    int v1 = (2 * tid + 1 < NBUCK) ? bcur[2 * tid + 1] : 0;
    ps[tid] = v0 + v1;
    __syncthreads();
    for (int off = 1; off < 256; off <<= 1) {
        int x = (tid >= off) ? ps[tid - off] : 0;
        __syncthreads();
        ps[tid] += x;
        __syncthreads();
    }
    {
        int ex = ps[tid] - (v0 + v1);
        pbase[2 * tid] = ex;
        pbase[2 * tid + 1] = ex + v0;
    }
    __syncthreads();
    const int base = pbase[b];

    int nE = bcur[b];
    if (nE > BCAP) nE = BCAP;
    const int node0 = b * BNODE;
    const uint_t* tp = tmp + (size_t)b * BCAP;

    for (int t = tid; t < 512; t += 256) cnt[t] = 0;
    __syncthreads();
    for (int i = tid; i < nE; i += 256)
        atomicAdd(&cnt[tp[i] & 511], 1);
    __syncthreads();
    int a0 = cnt[2 * tid], a1 = cnt[2 * tid + 1];
    ps[tid] = a0 + a1;
    __syncthreads();
    for (int off = 1; off < 256; off <<= 1) {
        int x = (tid >= off) ? ps[tid - off] : 0;
        __syncthreads();
        ps[tid] += x;
        __syncthreads();
    }
    int ex = ps[tid] - (a0 + a1);
    offl[2 * tid] = ex;
    offl[2 * tid + 1] = ex + a0;
    __syncthreads();
    for (int t = tid; t < BNODE; t += 256) {
        int gn = node0 + t;
        if (gn < N_TOT) offs[gn] = base + offl[t];
    }
    if (b == NBUCK - 1 && tid == 0) offs[N_TOT] = base + nE;
    for (int t = tid; t < 512; t += 256) cnt[t] = 0;
    __syncthreads();
    for (int i = tid; i < nE; i += 256) {
        uint_t pk = tp[i];
        int ld = pk & 511;
        int p = atomicAdd(&cnt[ld], 1);
        csr[base + offl[ld] + p] = (int)(pk >> 9);
    }
}

// ====== softmax gather (round-14 best): 4 slots x 16 lanes, 2-deep ======
__global__ __launch_bounds__(256) void gat_gather6(
    const int* __restrict__ csrc, const int* __restrict__ offs,
    int base0, int nPerRep,
    const float* __restrict__ elr, int elrStride,
    const ushort_t* __restrict__ P, int pStride,
    ushort_t* __restrict__ out, int outStride)
{
    const int wv = threadIdx.x >> 6;
    const int g = blockIdx.x * 4 + wv;
    if (g >= 3 * nPerRep) return;
    const int rep = g / nPerRep;
    const int node = g - rep * nPerRep;
    const float* elrp = elr + (size_t)rep * elrStride;
    const ushort_t* Pp = P + (size_t)rep * pStride;
    ushort_t* outp = out + (size_t)rep * outStride;

    const int l = threadIdx.x & 63;
    const uint_t lane16 = l & 15;
    const int slot = l >> 4;
    const uint_t hg = lane16 >> 2;
    const int beg = offs[base0 + g], end = offs[base0 + g + 1];
    const float erg = elrp[(uint_t)node * 8u + 4u + hg];
    float den = 0.f;
    float a0 = 0.f, a1 = 0.f, a2 = 0.f, a3 = 0.f;
    float a4 = 0.f, a5 = 0.f, a6 = 0.f, a7 = 0.f;
    int i = beg + slot;
    for (; i + 4 < end; i += 8) {
        uint_t s0 = (uint_t)csrc[i];
        uint_t s1 = (uint_t)csrc[i + 4];
        float w0 = __expf(lrelu(elrp[s0 * 8u + hg] + erg, 0.2f));
        float w1 = __expf(lrelu(elrp[s1 * 8u + hg] + erg, 0.2f));
        uint4 d0 = *(const uint4*)(Pp + s0 * 128u + lane16 * 8u);
        uint4 d1 = *(const uint4*)(Pp + s1 * 128u + lane16 * 8u);
        den += w0 + w1;
        a0 += w0 * bf_lo(d0.x) + w1 * bf_lo(d1.x);
        a1 += w0 * bf_hi(d0.x) + w1 * bf_hi(d1.x);
        a2 += w0 * bf_lo(d0.y) + w1 * bf_lo(d1.y);
        a3 += w0 * bf_hi(d0.y) + w1 * bf_hi(d1.y);
        a4 += w0 * bf_lo(d0.z) + w1 * bf_lo(d1.z);
        a5 += w0 * bf_hi(d0.z) + w1 * bf_hi(d1.z);
        a6 += w0 * bf_lo(d0.w) + w1 * bf_lo(d1.w);
        a7 += w0 * bf_hi(d0.w) + w1 * bf_hi(d1.w);
    }
    if (i < end) {
        uint_t s0 = (uint_t)csrc[i];
        float w0 = __expf(lrelu(elrp[s0 * 8u + hg] + erg, 0.2f));
        uint4 d0 = *(const uint4*)(Pp + s0 * 128u + lane16 * 8u);
        den += w0;
        a0 += w0 * bf_lo(d0.x); a1 += w0 * bf_hi(d0.x);
        a2 += w0 * bf_lo(d0.y); a3 += w0 * bf_hi(d0.y);
        a4 += w0 * bf_lo(d0.z); a5 += w0 * bf_hi(d0.z);
        a6 += w0 * bf_lo(d0.w); a7 += w0 * bf_hi(d0.w);
    }
    #pragma unroll
    for (int m = 16; m <= 32; m <<= 1) {
        den += __shfl_xor(den, m);
        a0 += __shfl_xor(a0, m); a1 += __shfl_xor(a1, m);
        a2 += __shfl_xor(a2, m); a3 += __shfl_xor(a3, m);
        a4 += __shfl_xor(a4, m); a5 += __shfl_xor(a5, m);
        a6 += __shfl_xor(a6, m); a7 += __shfl_xor(a7, m);
    }
    if (slot == 0) {
        float inv = (end > beg) ? 1.f / den : 0.f;
        uint4 pk;
        pk.x = cvt2(lrelu(a0 * inv, 0.01f), lrelu(a1 * inv, 0.01f));
        pk.y = cvt2(lrelu(a2 * inv, 0.01f), lrelu(a3 * inv, 0.01f));
        pk.z = cvt2(lrelu(a4 * inv, 0.01f), lrelu(a5 * inv, 0.01f));
        pk.w = cvt2(lrelu(a6 * inv, 0.01f), lrelu(a7 * inv, 0.01f));
        *(uint4*)(outp + (uint_t)node * 128u + lane16 * 8u) = pk;
    }
}

// ================= final linear 128 -> 2 =================
__global__ __launch_bounds__(256) void lin_kernel(
    const float* __restrict__ H, const float* __restrict__ W,
    const float* __restrict__ b, float* __restrict__ out, int n)
{
    int idx = blockIdx.x * 256 + threadIdx.x;
    int node = idx >> 1, c = idx & 1;
    if (node >= n) return;
    float acc = 0.f;
    for (int k = 0; k < 128; ++k)
        acc += H[(size_t)node * 128 + k] * W[k * 2 + c];
    out[(size_t)node * 2 + c] = acc + b[c];
}

extern "C" void kernel_launch(void* const* d_in, const int* in_sizes, int n_in,
                              void* d_out, int out_size, void* d_ws, size_t ws_size,
                              hipStream_t stream)
{
    (void)in_sizes; (void)n_in; (void)out_size; (void)ws_size;
    const float* x       = (const float*)d_in[0];
    const int*   src0    = (const int*)d_in[1];
    const int*   dst0    = (const int*)d_in[2];
    const int*   src1    = (const int*)d_in[3];
    const int*   dst1    = (const int*)d_in[4];
    const float* conv_W  = (const float*)d_in[5];
    const float* conv_al = (const float*)d_in[6];
    const float* conv_ar = (const float*)d_in[7];
    const float* feat_W  = (const float*)d_in[8];
    const float* feat_b  = (const float*)d_in[9];
    const float* relWl_W = (const float*)d_in[10];
    const float* relWl_b = (const float*)d_in[11];
    const float* relWr_W = (const float*)d_in[12];
    const float* relWr_b = (const float*)d_in[13];
    const float* relP_W  = (const float*)d_in[14];
    const float* relP_b  = (const float*)d_in[15];
    const float* rela_W  = (const float*)d_in[16];
    const float* proj_W  = (const float*)d_in[18];
    const float* proj_b  = (const float*)d_in[19];
    const float* hopWl_W = (const float*)d_in[20];
    const float* hopWl_b = (const float*)d_in[21];
    const float* hopWr_W = (const float*)d_in[22];
    const float* hopWr_b = (const float*)d_in[23];
    const float* hopP_W  = (const float*)d_in[24];
    const float* hopP_b  = (const float*)d_in[25];
    const float* hopa_W  = (const float*)d_in[26];
    const float* lin_W   = (const float*)d_in[28];
    const float* lin_b   = (const float*)d_in[29];
    float* out = (float*)d_out;

    // ---- workspace layout (~233 MB) ----
    char* base = (char*)d_ws;
    size_t off = 0;
    auto alloc = [&](size_t bytes) -> void* {
        void* p = base + off;
        off += (bytes + 255) & ~(size_t)255;
        return p;
    };
    ushort_t* P     = (ushort_t*)alloc((size_t)3 * N0 * 128 * 2);
    float* elr      = (float*)alloc((size_t)3 * N0 * 8 * 4);
    ushort_t* x16   = (ushort_t*)alloc((size_t)N0 * 128 * 2);
    ushort_t* F     = (ushort_t*)alloc((size_t)3 * N1 * 128 * 2);
    ushort_t* F3    = (ushort_t*)alloc((size_t)N1 * 128 * 2);
    ushort_t* h1    = (ushort_t*)alloc((size_t)N1 * 128 * 2);
    ushort_t* h2    = (ushort_t*)alloc((size_t)N2 * 128 * 2);
    float* glbuf    = (float*)alloc((size_t)N1 * 128 * 4);
    float* glhop    = (float*)alloc((size_t)N2 * 128 * 4);
    int*   csr_all  = (int*)alloc((size_t)NE_ALL * 4);
    int*   offs     = (int*)alloc((size_t)(N_TOT + 1) * 4);
    int*   bcur     = (int*)alloc(512 * 4);
    ushort_t* pconvA = (ushort_t*)alloc((size_t)6 * 136 * 128 * 2);
    ushort_t* p2L0 = (ushort_t*)alloc(256 * 128 * 2);
    ushort_t* p2L1 = (ushort_t*)alloc(256 * 128 * 2);
    ushort_t* pE   = (ushort_t*)alloc(256 * 128 * 2);
    ushort_t* pF0  = (ushort_t*)alloc(256 * 128 * 2);
    ushort_t* pF1  = (ushort_t*)alloc(256 * 128 * 2);
    ushort_t* pG   = (ushort_t*)alloc(256 * 128 * 2);

    ushort_t* F0 = F;
    ushort_t* F1 = F + (size_t)N1 * 128;
    ushort_t* F2 = F + (size_t)2 * N1 * 128;
    ushort_t* hopp0 = F0;
    float* hout  = glbuf;
    uint_t* tmp  = (uint_t*)F;

    // ---- merged prologue ----
    PrepArgs pa;
    pa.conv_W = conv_W; pa.conv_al = conv_al; pa.conv_ar = conv_ar; pa.pconvA = pconvA;
    pa.j[0] = {feat_W, relWl_W, p2L0};
    pa.j[1] = {feat_W + 16384, relWl_W + 16384, p2L1};
    pa.j[2] = {proj_W, hopWl_W, pE};
    pa.j[3] = {relWr_W, relP_W, pF0};
    pa.j[4] = {relWr_W + 16384, relP_W + 16384, pF1};
    pa.j[5] = {hopWr_W, hopP_W, pG};
    pa.x = x; pa.x16 = x16;
    prep_all<<<816 + 1536 + 12500, 128, 0, stream>>>(pa);

    // ---- binned CSR build ----
    hipMemsetAsync(bcur, 0, 512 * 4, stream);
    bin_pass<<<(NE_ALL + 4095) / 4096, 256, 0, stream>>>(src0, dst0, src1, dst1, bcur, tmp);
    build_pass2<<<NBUCK, 256, 0, stream>>>(bcur, tmp, offs, csr_all);

    // ---- layer 0 ----
    gemm_bf16<9, 1, 1, 1, 0, 1><<<dim3((N0 + 127) / 128, 3), 256, 0, stream>>>(
        x16, x16, x16, x16, N0, pconvA, 136, nullptr, nullptr, 128, 1.f, 1.f,
        P, 128, elr, 8, nullptr, nullptr, 0,
        136 * 128, N0 * 128, N0 * 8);
    gat_gather6<<<(3 * N1 + 3) / 4, 256, 0, stream>>>(
        csr_all, offs, 0, N1, elr, N0 * 8, P, N0 * 128, F, N1 * 128);
    gemm_bf16<8, 1, 1, 1><<<dim3((N1 + 127) / 128, 2), 256, 0, stream>>>(
        x16, x16, x16, x16, N1, p2L0, 256, feat_b, relWl_b, 128, 0.01f, 1.f,
        F3, 128, glbuf, 128, nullptr, nullptr, 0);
    gemm_bf16<4, 4, 4, 1, 1><<<dim3((N1 * 4 + 127) / 128, 2), 256, 0, stream>>>(
        F0, F1, F2, F3, N1, pF0, 256, relWr_b, relP_b, 128, 1.f, 1.f,
        h1, 128, nullptr, 0, glbuf, rela_W, 4);

    // ---- layer 1 ----
    gemm_bf16<9, 1, 1, 1, 0, 1><<<dim3((N1 + 127) / 128, 3), 256, 0, stream>>>(
        h1, h1, h1, h1, N1, pconvA + (size_t)3 * 136 * 128, 136,
        nullptr, nullptr, 128, 1.f, 1.f,
        P, 128, elr, 8, nullptr, nullptr, 0,
        136 * 128, N0 * 128, N0 * 8);
    gat_gather6<<<(3 * N2 + 3) / 4, 256, 0, stream>>>(
        csr_all, offs, 3 * N1, N2, elr, N0 * 8, P, N0 * 128, F, N1 * 128);
    gemm_bf16<8, 1, 1, 1><<<dim3((N2 + 127) / 128, 2), 256, 0, stream>>>(
        h1, h1, h1, h1, N2, p2L1, 256, feat_b + 128, relWl_b + 128, 128, 0.01f, 1.f,
        F3, 128, glbuf, 128, nullptr, nullptr, 0);
    gemm_bf16<4, 4, 4, 1, 1><<<dim3((N2 * 4 + 127) / 128, 2), 256, 0, stream>>>(
        F0, F1, F2, F3, N2, pF1, 256, relWr_b + 128, relP_b + 128, 128, 1.f, 1.f,
        h2, 128, nullptr, 0, glbuf, rela_W + 16, 4);

    // ---- proj + hop gl ----
    gemm_bf16<8, 1, 1, 1><<<dim3((N2 + 127) / 128, 2), 256, 0, stream>>>(
        x16, x16, x16, x16, N2, pE, 256, proj_b, hopWl_b, 128, 1.f, 1.f,
        hopp0, 128, glhop, 128, nullptr, nullptr, 0);

    // ---- hop attention over [proj, h1[:N2], h2] ----
    gemm_bf16<4, 4, 4, 1, 0><<<dim3((N2 * 4 + 127) / 128, 2), 256, 0, stream>>>(
        hopp0, h1, h2, hopp0, N2, pG, 256, hopWr_b, hopP_b, 128, 1.f, 1.f,
        hout, 128, nullptr, 0, glhop, hopa_W, 3);

    // ---- final linear ----
    lin_kernel<<<(N2 * 2 + 255) / 256, 256, 0, stream>>>(hout, lin_W, lin_b, out, N2);
}